// Round 1
// baseline (4308.182 us; speedup 1.0000x reference)
//
#include <hip/hip_runtime.h>

// GCN: 3 layers of GraphConv (norm='both') on N=50000 nodes, E=800000 edges, D=128.
// h <- (in_norm ⊙ segsum_dst(out_norm ⊙ h)[src->dst]) @ W_i + b_i
//
// Round-0 structure:
//   k_deg      : atomic degree counts (f32) for src/dst
//   k_norm     : deg -> rsqrt(max(deg,1)) in place
//   k_scatter  : per edge, gather h[src]*out_norm[src] (float4 x 32 threads) and
//                atomicAdd into agg[dst]
//   k_gemm     : in-place row GEMM: x[row] = (x[row]*in_norm[row]) @ W + b,
//                W staged in 64KB LDS, float2 outputs per thread.

#define NN 50000
#define NE 800000
#define DM 128

__global__ void k_deg(const int* __restrict__ src, const int* __restrict__ dst,
                      float* __restrict__ outd, float* __restrict__ ind) {
  int e = blockIdx.x * blockDim.x + threadIdx.x;
  if (e < NE) {
    atomicAdd(&outd[src[e]], 1.0f);
    atomicAdd(&ind[dst[e]], 1.0f);
  }
}

__global__ void k_norm(float* __restrict__ a, float* __restrict__ b, int n) {
  int i = blockIdx.x * blockDim.x + threadIdx.x;
  if (i < n) {
    a[i] = rsqrtf(fmaxf(a[i], 1.0f));
    b[i] = rsqrtf(fmaxf(b[i], 1.0f));
  }
}

// 32 threads per edge; each thread handles 4 consecutive floats (float4).
__global__ void k_scatter(const float* __restrict__ h, const int* __restrict__ src,
                          const int* __restrict__ dst, const float* __restrict__ onorm,
                          float* __restrict__ agg) {
  long long tid = (long long)blockIdx.x * blockDim.x + threadIdx.x;
  int e = (int)(tid >> 5);
  if (e >= NE) return;
  int l = (int)(tid & 31);
  int s = src[e];
  int d = dst[e];
  float nv = onorm[s];
  float4 v = reinterpret_cast<const float4*>(h + (size_t)s * DM)[l];
  float* o = agg + (size_t)d * DM + l * 4;
  atomicAdd(o + 0, v.x * nv);
  atomicAdd(o + 1, v.y * nv);
  atomicAdd(o + 2, v.z * nv);
  atomicAdd(o + 3, v.w * nv);
}

// In-place row GEMM. Block = 256 threads = 4 row-slots (tid>>6) x 64 threads.
// Each thread computes 2 consecutive outputs (float2). Grid=1250, 10 passes:
// rows = pass*5000 + blockIdx.x*4 + sub, covers exactly 50000 rows.
__launch_bounds__(256, 2)
__global__ void k_gemm(float* __restrict__ x, const float* __restrict__ W,
                       const float* __restrict__ bias, const float* __restrict__ inorm) {
  __shared__ float Wl[DM * DM];   // 64 KB
  __shared__ float xs[4][DM];     // 2 KB

  // stage W into LDS (float4 coalesced)
  for (int i = threadIdx.x; i < DM * DM / 4; i += blockDim.x) {
    reinterpret_cast<float4*>(Wl)[i] = reinterpret_cast<const float4*>(W)[i];
  }

  int sub = threadIdx.x >> 6;          // 0..3 row slot (wave-uniform)
  int lj  = (threadIdx.x & 63) * 2;    // output pair index
  float2 bj = *reinterpret_cast<const float2*>(bias + lj);
  __syncthreads();

  for (int p = 0; p < 10; ++p) {
    int row = p * 5000 + blockIdx.x * 4 + sub;
    // load + scale row into LDS (each of 64 threads loads 2 floats)
    float sc = inorm[row];
    float2 xv = *reinterpret_cast<const float2*>(x + (size_t)row * DM + lj);
    xs[sub][lj]     = xv.x * sc;
    xs[sub][lj + 1] = xv.y * sc;
    __syncthreads();

    float2 acc = bj;
#pragma unroll
    for (int k = 0; k < DM; ++k) {
      float xk = xs[sub][k];  // wave-uniform broadcast
      float2 w = *reinterpret_cast<const float2*>(&Wl[k * DM + lj]);
      acc.x += xk * w.x;
      acc.y += xk * w.y;
    }
    __syncthreads();  // xs consumed; safe to overwrite next pass
    *reinterpret_cast<float2*>(x + (size_t)row * DM + lj) = acc;
  }
}

extern "C" void kernel_launch(void* const* d_in, const int* in_sizes, int n_in,
                              void* d_out, int out_size, void* d_ws, size_t ws_size,
                              hipStream_t stream) {
  const float* in_feat = (const float*)d_in[0];
  const int*   ei      = (const int*)d_in[1];
  const float* Ws      = (const float*)d_in[2];
  const float* bs      = (const float*)d_in[3];
  float* out = (float*)d_out;
  float* ws  = (float*)d_ws;

  const int* src = ei;
  const int* dst = ei + NE;

  float* onorm = ws;                 // NN
  float* inorm = ws + NN;            // NN
  float* bufA  = ws + 2 * NN;        // NN*DM
  float* bufB  = bufA + (size_t)NN * DM;

  // degrees -> norms
  hipMemsetAsync(onorm, 0, 2 * (size_t)NN * sizeof(float), stream);
  k_deg<<<(NE + 255) / 256, 256, 0, stream>>>(src, dst, onorm, inorm);
  k_norm<<<(NN + 255) / 256, 256, 0, stream>>>(onorm, inorm, NN);

  const float* hin[3] = {in_feat, bufA, bufB};
  float*       agg[3] = {bufA, bufB, out};

  for (int i = 0; i < 3; ++i) {
    hipMemsetAsync(agg[i], 0, (size_t)NN * DM * sizeof(float), stream);
    k_scatter<<<(NE * 32) / 256, 256, 0, stream>>>(hin[i], src, dst, onorm, agg[i]);
    k_gemm<<<1250, 256, 0, stream>>>(agg[i], Ws + (size_t)i * DM * DM, bs + (size_t)i * DM, inorm);
  }
}

// Round 3
// 677.071 us; speedup vs baseline: 6.3630x; 6.3630x over previous
//
#include <hip/hip_runtime.h>

// GCN: 3 layers GraphConv (norm='both'), N=50000, E=800000, D=128.
// Round 1: scatter-atomics -> CSR gather (no fp atomics).
//   k_count : int degree counts for src/dst
//   k_norms : rsqrt(max(deg,1)) norms from counts
//   k_scan  : single-block exclusive scan of in-degree -> rowptr + cursor
//   k_fill  : CSR column fill via atomic cursors
//   k_gather: per dest node, 32 lanes x float4 register accumulate over edges;
//             onorm folded into inner loop, inorm into epilogue
//   k_gemm  : in-place row GEMM x = x @ W + b, W staged in 64KB LDS

#define NN 50000
#define NE 800000
#define DM 128

__global__ void k_count(const int* __restrict__ src, const int* __restrict__ dst,
                        int* __restrict__ co, int* __restrict__ ci) {
  int e = blockIdx.x * blockDim.x + threadIdx.x;
  if (e < NE) {
    atomicAdd(&co[src[e]], 1);
    atomicAdd(&ci[dst[e]], 1);
  }
}

__global__ void k_norms(const int* __restrict__ co, const int* __restrict__ ci,
                        float* __restrict__ onorm, float* __restrict__ inorm) {
  int i = blockIdx.x * blockDim.x + threadIdx.x;
  if (i < NN) {
    onorm[i] = rsqrtf(fmaxf((float)co[i], 1.0f));
    inorm[i] = rsqrtf(fmaxf((float)ci[i], 1.0f));
  }
}

// Single block, 1024 threads. Exclusive scan of ci[0..NN) -> rowptr, cursor.
__global__ void k_scan(const int* __restrict__ ci, int* __restrict__ rowptr,
                       int* __restrict__ cursor) {
  __shared__ int part[1024];
  const int CH = (NN + 1023) / 1024;  // 49 elements per thread
  int t = threadIdx.x;
  int base = t * CH;
  int sum = 0;
  for (int i = 0; i < CH; ++i) {
    int idx = base + i;
    if (idx < NN) sum += ci[idx];
  }
  part[t] = sum;
  __syncthreads();
  // Hillis-Steele inclusive scan over 1024 partials
  for (int off = 1; off < 1024; off <<= 1) {
    int v = (t >= off) ? part[t - off] : 0;
    __syncthreads();
    part[t] += v;
    __syncthreads();
  }
  int run = (t == 0) ? 0 : part[t - 1];
  for (int i = 0; i < CH; ++i) {
    int idx = base + i;
    if (idx < NN) {
      rowptr[idx] = run;
      cursor[idx] = run;
      run += ci[idx];
    }
  }
  if (t == 0) rowptr[NN] = NE;
}

__global__ void k_fill(const int* __restrict__ src, const int* __restrict__ dst,
                       int* __restrict__ cursor, int* __restrict__ col) {
  int e = blockIdx.x * blockDim.x + threadIdx.x;
  if (e < NE) {
    int p = atomicAdd(&cursor[dst[e]], 1);
    col[p] = src[e];
  }
}

// 32 lanes per destination node, float4 per lane (32*16B = 512B = one row).
__global__ void k_gather(const float* __restrict__ h, const int* __restrict__ rowptr,
                         const int* __restrict__ col, const float* __restrict__ onorm,
                         const float* __restrict__ inorm, float* __restrict__ agg) {
  int tid = blockIdx.x * blockDim.x + threadIdx.x;
  int n = tid >> 5;
  if (n >= NN) return;
  int lane = tid & 31;
  int beg = rowptr[n];
  int end = rowptr[n + 1];
  const float4* h4 = reinterpret_cast<const float4*>(h);
  float4 acc = make_float4(0.f, 0.f, 0.f, 0.f);
  for (int e = beg; e < end; ++e) {
    int s = col[e];
    float nv = onorm[s];
    float4 v = h4[s * 32 + lane];
    acc.x += v.x * nv;
    acc.y += v.y * nv;
    acc.z += v.z * nv;
    acc.w += v.w * nv;
  }
  float sc = inorm[n];
  float4 o = make_float4(acc.x * sc, acc.y * sc, acc.z * sc, acc.w * sc);
  reinterpret_cast<float4*>(agg)[n * 32 + lane] = o;
}

// In-place row GEMM. Block = 256 threads = 4 row-slots x 64 threads; each
// thread computes 2 consecutive outputs. Grid=1250, 10 passes over rows.
__launch_bounds__(256, 2)
__global__ void k_gemm(float* __restrict__ x, const float* __restrict__ W,
                       const float* __restrict__ bias) {
  __shared__ float Wl[DM * DM];   // 64 KB
  __shared__ float xs[4][DM];

  for (int i = threadIdx.x; i < DM * DM / 4; i += blockDim.x) {
    reinterpret_cast<float4*>(Wl)[i] = reinterpret_cast<const float4*>(W)[i];
  }

  int sub = threadIdx.x >> 6;
  int lj  = (threadIdx.x & 63) * 2;
  float2 bj = *reinterpret_cast<const float2*>(bias + lj);
  __syncthreads();

  for (int p = 0; p < 10; ++p) {
    int row = p * 5000 + blockIdx.x * 4 + sub;
    float2 xv = *reinterpret_cast<const float2*>(x + (size_t)row * DM + lj);
    xs[sub][lj]     = xv.x;
    xs[sub][lj + 1] = xv.y;
    __syncthreads();

    float2 acc = bj;
#pragma unroll
    for (int k = 0; k < DM; ++k) {
      float xk = xs[sub][k];
      float2 w = *reinterpret_cast<const float2*>(&Wl[k * DM + lj]);
      acc.x += xk * w.x;
      acc.y += xk * w.y;
    }
    __syncthreads();
    *reinterpret_cast<float2*>(x + (size_t)row * DM + lj) = acc;
  }
}

extern "C" void kernel_launch(void* const* d_in, const int* in_sizes, int n_in,
                              void* d_out, int out_size, void* d_ws, size_t ws_size,
                              hipStream_t stream) {
  const float* in_feat = (const float*)d_in[0];
  const int*   ei      = (const int*)d_in[1];
  const float* Ws      = (const float*)d_in[2];
  const float* bs      = (const float*)d_in[3];
  float* out = (float*)d_out;

  const int* src = ei;
  const int* dst = ei + NE;

  // workspace layout
  char* w = (char*)d_ws;
  int* co     = (int*)w;            w += NN * sizeof(int);
  int* ci     = (int*)w;            w += NN * sizeof(int);
  int* rowptr = (int*)w;            w += (NN + 1) * sizeof(int);
  int* cursor = (int*)w;            w += NN * sizeof(int);
  int* col    = (int*)w;            w += NE * sizeof(int);
  float* onorm = (float*)w;         w += NN * sizeof(float);
  float* inorm = (float*)w;         w += NN * sizeof(float);
  float* bufA  = (float*)w;         w += (size_t)NN * DM * sizeof(float);
  float* bufB  = (float*)w;         /* w += NN*DM*4 */

  hipMemsetAsync(co, 0, 2 * NN * sizeof(int), stream);  // co+ci contiguous
  k_count<<<(NE + 255) / 256, 256, 0, stream>>>(src, dst, co, ci);
  k_norms<<<(NN + 255) / 256, 256, 0, stream>>>(co, ci, onorm, inorm);
  k_scan<<<1, 1024, 0, stream>>>(ci, rowptr, cursor);
  k_fill<<<(NE + 255) / 256, 256, 0, stream>>>(src, dst, cursor, col);

  const float* hin[3] = {in_feat, bufA, bufB};
  float*       hout[3] = {bufA, bufB, out};

  for (int i = 0; i < 3; ++i) {
    k_gather<<<(NN * 32 + 255) / 256, 256, 0, stream>>>(hin[i], rowptr, col, onorm,
                                                        inorm, hout[i]);
    k_gemm<<<1250, 256, 0, stream>>>(hout[i], Ws + (size_t)i * DM * DM, bs + (size_t)i * DM);
  }
}